// Round 12
// baseline (353.837 us; speedup 1.0000x reference)
//
#include <hip/hip_runtime.h>

#define NN 100000
#define NE 1250000
#define DD 64
#define NBKT 391            // buckets of 256 nodes: 391*256 = 100096 >= NN
#define NCNT NBKT           // counters per direction
#define NCNT2 (2 * NCNT)    // 782
#define CHUNK 8192
#define NCHUNK ((NE + CHUNK - 1) / CHUNK)  // 153
#define HBLK 256            // histogram blocks
#define SORT_CAP 4096       // per-(bucket,dir) record capacity (avg 3200)
#define TSTR 68             // node-kernel LDS tile stride (f32), pad 4

typedef __attribute__((ext_vector_type(8))) short bf16x8_t;
typedef __attribute__((ext_vector_type(4))) float f32x4_t;

__device__ __forceinline__ unsigned short bf16_rne(float v) {
  unsigned u = __builtin_bit_cast(unsigned, v);
  u += 0x7FFFu + ((u >> 16) & 1u);
  return (unsigned short)(u >> 16);
}
__device__ __forceinline__ void split_bf16(float v, unsigned short& hi,
                                           unsigned short& lo) {
  hi = bf16_rne(v);
  const float fh = __builtin_bit_cast(float, ((unsigned)hi) << 16);
  lo = bf16_rne(v - fh);
}

// ---------------- precompute: Wc1 = W2 @ Wl[64:128], Wc2 = W2 @ Wl[128:192],
// ----------------             bc = b_lin + b2 @ (Wl[64:128] + Wl[128:192])
__global__ __launch_bounds__(256) void precompute_kernel(
    const float* __restrict__ W2, const float* __restrict__ b2,
    const float* __restrict__ Wl, const float* __restrict__ bl,
    float* __restrict__ Wc1, float* __restrict__ Wc2, float* __restrict__ bc) {
  const int t = blockIdx.x * 256 + threadIdx.x;  // 32 blocks x 256 = 8192
  const int m = t >> 12;                         // 0 -> Wc1, 1 -> Wc2
  const int ij = t & 4095;
  const int i = ij >> 6, j = ij & 63;
  const float* Wp = Wl + (m ? 128 : 64) * 64;
  float s = 0.f;
#pragma unroll 8
  for (int k = 0; k < 64; ++k) s = fmaf(W2[i * 64 + k], Wp[k * 64 + j], s);
  if (m) Wc2[ij] = s; else Wc1[ij] = s;
  if (t < 64) {
    float sb = bl[t];
    for (int k = 0; k < 64; ++k)
      sb = fmaf(b2[k], Wl[(64 + k) * 64 + t] + Wl[(128 + k) * 64 + t], sb);
    bc[t] = sb;
  }
}

// ---------------- pack weights into MFMA B-fragment order (hi/lo bf16) -----
__global__ __launch_bounds__(256) void pack_w_kernel(
    const float* __restrict__ W1, const float* __restrict__ Wl,
    const float* __restrict__ Wc1, const float* __restrict__ Wc2,
    unsigned short* __restrict__ whi, unsigned short* __restrict__ wlo) {
  const int g = blockIdx.x * 256 + threadIdx.x;
  if (g >= 4 * 4096) return;
  const int mat = g >> 12;
  const int idx = g & 4095;
  const int i = idx & 7;
  const int lane = (idx >> 3) & 63;
  const int ct = (idx >> 9) & 3;
  const int ks = (idx >> 11) & 1;
  const int k = ks * 32 + ((lane >> 4) << 2) + (i & 3) + ((i >> 2) << 4);
  const int col = ct * 16 + (lane & 15);
  const float* src = (mat == 0) ? W1 : (mat == 1) ? Wc1 : (mat == 2) ? Wc2 : Wl;
  const float v = src[k * 64 + col];
  unsigned short h, l;
  split_bf16(v, h, l);
  whi[g] = h;
  wlo[g] = l;
}

// ---------------- LDS-privatized bucket histogram ----------------
__global__ __launch_bounds__(256) void bucket_hist_kernel(
    const int* __restrict__ ei, int* __restrict__ bcnt) {
  __shared__ int h[NCNT2];
  const int t = threadIdx.x;
  for (int i = t; i < NCNT2; i += 256) h[i] = 0;
  __syncthreads();
  const int stride = 256 * HBLK;
  for (int e = blockIdx.x * 256 + t; e < NE; e += stride) {
    atomicAdd(&h[ei[NE + e] >> 8], 1);         // dir 0: keyed by dst
    atomicAdd(&h[NBKT + (ei[e] >> 8)], 1);     // dir 1: keyed by src
  }
  __syncthreads();
  for (int i = t; i < NCNT2; i += 256) {
    const int c = h[i];
    if (c) atomicAdd(&bcnt[i], c);
  }
}

// single block, 1024 threads, scans all 782 counters into region bases.
__global__ __launch_bounds__(1024) void bucket_scan_kernel(
    const int* __restrict__ bcnt, int* __restrict__ bbase,
    int* __restrict__ bcur2) {
  __shared__ int part[1024];
  const int t = threadIdx.x;
  int v[4];
  int s = 0;
#pragma unroll
  for (int i = 0; i < 4; ++i) {
    const int idx = t * 4 + i;
    v[i] = (idx < NCNT2) ? bcnt[idx] : 0;
    s += v[i];
  }
  part[t] = s;
  __syncthreads();
  int acc = s;
  for (int d = 1; d < 1024; d <<= 1) {
    const int add = (t >= d) ? part[t - d] : 0;
    __syncthreads();
    acc += add;
    part[t] = acc;
    __syncthreads();
  }
  int pre = acc - s;  // exclusive prefix for this thread's 4 counters
#pragma unroll
  for (int i = 0; i < 4; ++i) {
    const int idx = t * 4 + i;
    if (idx < NCNT2) {
      bbase[idx] = pre;
      bcur2[idx] = pre;
    }
    pre += v[i];
  }
  if (t == 0) bbase[NCNT2] = 2 * NE;  // sentinel
}

// ---------------- multisplit scatter: coalesced bucket-grouped records -----
// record: (e << 8) | key_in_bucket  (e < 2^21, key < 256 -> 29 bits)
__global__ __launch_bounds__(256) void multisplit_kernel(
    const int* __restrict__ ei, int* __restrict__ bcur2,
    int* __restrict__ tmp) {
  __shared__ int recs[CHUNK];       // 32 KB
  __shared__ int hist[NBKT];
  __shared__ int hbase[NBKT + 1];
  __shared__ int hcur[NBKT];
  __shared__ int gbase[NBKT];
  __shared__ int scanbuf[256];
  const int t = threadIdx.x;
  const int dir = (blockIdx.x >= NCHUNK) ? 1 : 0;
  const int chunk = blockIdx.x - (dir ? NCHUNK : 0);
  const int e0 = chunk * CHUNK;
  const int cnt = min(CHUNK, NE - e0);
  const int* keys = ei + (dir ? 0 : NE);  // dir0: key=dst; dir1: key=src
  for (int i = t; i < NBKT; i += 256) {
    hist[i] = 0;
    hcur[i] = 0;
  }
  __syncthreads();
  for (int i = t; i < cnt; i += 256) atomicAdd(&hist[keys[e0 + i] >> 8], 1);
  __syncthreads();
  const int i0 = 2 * t, i1 = 2 * t + 1;
  const int s0 = (i0 < NBKT) ? hist[i0] : 0;
  const int s1 = (i1 < NBKT) ? hist[i1] : 0;
  const int ps = s0 + s1;
  scanbuf[t] = ps;
  __syncthreads();
  int acc = ps;
  for (int d = 1; d < 256; d <<= 1) {
    const int add = (t >= d) ? scanbuf[t - d] : 0;
    __syncthreads();
    acc += add;
    scanbuf[t] = acc;
    __syncthreads();
  }
  const int pre = acc - ps;
  if (i0 < NBKT) hbase[i0] = pre;
  if (i1 < NBKT) hbase[i1] = pre + s0;
  if (t == 0) hbase[NBKT] = cnt;
  __syncthreads();
  for (int b = t; b < NBKT; b += 256) {
    const int c = hist[b];
    if (c > 0) gbase[b] = atomicAdd(&bcur2[dir * NBKT + b], c);
  }
  for (int i = t; i < cnt; i += 256) {
    const int n = keys[e0 + i];
    const int b = n >> 8;
    const int p = hbase[b] + atomicAdd(&hcur[b], 1);
    recs[p] = ((e0 + i) << 8) | (n & 255);
  }
  __syncthreads();
  for (int p = t; p < cnt; p += 256) {
    int lo = 0, hi = NBKT;
    while (hi - lo > 1) {
      const int mid = (lo + hi) >> 1;
      if (hbase[mid] <= p) lo = mid;
      else hi = mid;
    }
    tmp[gbase[lo] + (p - hbase[lo])] = recs[p];
  }
}

// ---------------- fused per-bucket sort + gather ----------------
// One 512-thread block per (bucket, dir). Sort bucket's records in LDS
// (counting sort by key, partner prefetched during placement), then gather:
// 8 waves x 32 nodes, 8 slots x 8 lanes per node, accumulate from LDS lists.
__global__ __launch_bounds__(512) void sort_gather_kernel(
    const float* __restrict__ x, const float* __restrict__ ea,
    const int* __restrict__ ei, const int* __restrict__ tmp,
    const int* __restrict__ bbase, float* __restrict__ agg_in,
    float* __restrict__ agg_out) {
  __shared__ int2 srec[SORT_CAP];  // 32 KB sorted (e, partner)
  __shared__ int hist[256];
  __shared__ int offl[257];
  __shared__ int cur[256];
  __shared__ int scanbuf[256];
  const int t = threadIdx.x;
  const int isrc = (blockIdx.x >= NBKT) ? 1 : 0;
  const int bloc = blockIdx.x - (isrc ? NBKT : 0);
  const int cbase = (isrc ? NCNT : 0) + bloc;
  const int beg = bbase[cbase];
  const int end = bbase[cbase + 1];
  const int cnt = end - beg;
  const int* pbase = ei + (isrc ? NE : 0);  // partner array for this dir
  if (t < 256) hist[t] = 0;
  __syncthreads();
  for (int k = beg + t; k < end; k += 512) atomicAdd(&hist[tmp[k] & 255], 1);
  __syncthreads();
  // exclusive scan of 256 bins (threads < 256 active; barriers uniform)
  int v = 0, acc = 0;
  if (t < 256) {
    v = hist[t];
    acc = v;
    scanbuf[t] = v;
  }
  __syncthreads();
  for (int d = 1; d < 256; d <<= 1) {
    int add = 0;
    if (t < 256 && t >= d) add = scanbuf[t - d];
    __syncthreads();
    if (t < 256) {
      acc += add;
      scanbuf[t] = acc;
    }
    __syncthreads();
  }
  if (t < 256) {
    offl[t] = acc - v;
    cur[t] = acc - v;
  }
  if (t == 0) offl[256] = cnt;
  __syncthreads();
  // placement: re-read records (L2-hot), prefetch partner, store sorted
  for (int k = beg + t; k < end; k += 512) {
    const int r = tmp[k];
    const int e = (int)(((unsigned)r) >> 8);
    const int p = atomicAdd(&cur[r & 255], 1);
    if (p < SORT_CAP) srec[p] = make_int2(e, pbase[e]);
  }
  __syncthreads();
  // gather
  const int wv = t >> 6;
  const int lane = t & 63;
  const int slot = lane >> 3;
  const int q = lane & 7;
  const int c0 = q * 8;
  float* agg = isrc ? agg_out : agg_in;
  for (int nk = wv * 32; nk < wv * 32 + 32; ++nk) {
    const int n = bloc * 256 + nk;
    const int b2 = offl[nk];
    const int e2 = offl[nk + 1];
    float4 acc0 = make_float4(0.f, 0.f, 0.f, 0.f);
    float4 acc1 = make_float4(0.f, 0.f, 0.f, 0.f);
    for (int k = b2 + slot; k < e2; k += 8) {
      const int2 r = srec[k];
      const float* ar = ea + (size_t)r.x * DD + c0;
      const float* xr = x + (size_t)r.y * DD + c0;
      const float4 a0 = *reinterpret_cast<const float4*>(ar);
      const float4 a1 = *reinterpret_cast<const float4*>(ar + 4);
      const float4 x0 = *reinterpret_cast<const float4*>(xr);
      const float4 x1 = *reinterpret_cast<const float4*>(xr + 4);
      acc0.x += fmaxf(a0.x + x0.x, 0.f);
      acc0.y += fmaxf(a0.y + x0.y, 0.f);
      acc0.z += fmaxf(a0.z + x0.z, 0.f);
      acc0.w += fmaxf(a0.w + x0.w, 0.f);
      acc1.x += fmaxf(a1.x + x1.x, 0.f);
      acc1.y += fmaxf(a1.y + x1.y, 0.f);
      acc1.z += fmaxf(a1.z + x1.z, 0.f);
      acc1.w += fmaxf(a1.w + x1.w, 0.f);
    }
#pragma unroll
    for (int m = 8; m <= 32; m <<= 1) {
      acc0.x += __shfl_xor(acc0.x, m);
      acc0.y += __shfl_xor(acc0.y, m);
      acc0.z += __shfl_xor(acc0.z, m);
      acc0.w += __shfl_xor(acc0.w, m);
      acc1.x += __shfl_xor(acc1.x, m);
      acc1.y += __shfl_xor(acc1.y, m);
      acc1.z += __shfl_xor(acc1.z, m);
      acc1.w += __shfl_xor(acc1.w, m);
    }
    if (lane < 8 && n < NN) {
      float* p = agg + (size_t)n * DD + lane * 8;
      *reinterpret_cast<float4*>(p) = acc0;
      *reinterpret_cast<float4*>(p + 4) = acc1;
    }
  }
}

// ---------------- fallback edge pass (atomic) if ws too small -------------
__global__ __launch_bounds__(256) void edge_kernel(
    const float* __restrict__ x, const int* __restrict__ ei,
    const float* __restrict__ ea, float* __restrict__ agg_in,
    float* __restrict__ agg_out) {
  const int tid = blockIdx.x * 256 + threadIdx.x;
  const int e = tid >> 4;
  if (e >= NE) return;
  const int c = (tid & 15) * 4;
  const int s = ei[e];
  const int d = ei[NE + e];
  const float4 a = *reinterpret_cast<const float4*>(ea + (size_t)e * DD + c);
  const float4 xs = *reinterpret_cast<const float4*>(x + (size_t)s * DD + c);
  const float4 xd = *reinterpret_cast<const float4*>(x + (size_t)d * DD + c);
  float* pi = agg_in + (size_t)d * DD + c;
  unsafeAtomicAdd(pi + 0, fmaxf(xs.x + a.x, 0.f));
  unsafeAtomicAdd(pi + 1, fmaxf(xs.y + a.y, 0.f));
  unsafeAtomicAdd(pi + 2, fmaxf(xs.z + a.z, 0.f));
  unsafeAtomicAdd(pi + 3, fmaxf(xs.w + a.w, 0.f));
  float* po = agg_out + (size_t)s * DD + c;
  unsafeAtomicAdd(po + 0, fmaxf(xd.x + a.x, 0.f));
  unsafeAtomicAdd(po + 1, fmaxf(xd.y + a.y, 0.f));
  unsafeAtomicAdd(po + 2, fmaxf(xd.z + a.z, 0.f));
  unsafeAtomicAdd(po + 3, fmaxf(xd.w + a.w, 0.f));
}

// ---------------- MFMA node MLP + final projection ----------------
__device__ __forceinline__ void mm_pass(const float* At, int wv, int lane,
                                        const unsigned short* __restrict__ whi,
                                        const unsigned short* __restrict__ wlo,
                                        int mat, f32x4_t acc[4]) {
  const int row = (wv << 4) + (lane & 15);
  const int kbase = ((lane >> 4) & 3) << 2;
#pragma unroll
  for (int ks = 0; ks < 2; ++ks) {
    const float* ap = At + row * TSTR + ks * 32 + kbase;
    const float4 g0 = *reinterpret_cast<const float4*>(ap);
    const float4 g1 = *reinterpret_cast<const float4*>(ap + 16);
    const float gv[8] = {g0.x, g0.y, g0.z, g0.w, g1.x, g1.y, g1.z, g1.w};
    bf16x8_t ahi, alo;
#pragma unroll
    for (int i = 0; i < 8; ++i) {
      unsigned short h, l;
      split_bf16(gv[i], h, l);
      ahi[i] = (short)h;
      alo[i] = (short)l;
    }
#pragma unroll
    for (int ct = 0; ct < 4; ++ct) {
      const int fb = ((mat * 2 + ks) * 4 + ct) * 512 + lane * 8;
      const bf16x8_t wh = *reinterpret_cast<const bf16x8_t*>(whi + fb);
      const bf16x8_t wl = *reinterpret_cast<const bf16x8_t*>(wlo + fb);
      acc[ct] = __builtin_amdgcn_mfma_f32_16x16x32_bf16(ahi, wh, acc[ct], 0, 0, 0);
      acc[ct] = __builtin_amdgcn_mfma_f32_16x16x32_bf16(alo, wh, acc[ct], 0, 0, 0);
      acc[ct] = __builtin_amdgcn_mfma_f32_16x16x32_bf16(ahi, wl, acc[ct], 0, 0, 0);
    }
  }
}

__global__ __launch_bounds__(256) void node_kernel(
    const float* __restrict__ x, const float* __restrict__ agg_in,
    const float* __restrict__ agg_out, const float* __restrict__ b1,
    const float* __restrict__ bc, const unsigned short* __restrict__ whi,
    const unsigned short* __restrict__ wlo, float* __restrict__ out) {
  __shared__ float TA[64 * TSTR];
  __shared__ float TH[64 * TSTR];
  const int t = threadIdx.x;
  const int lane = t & 63;
  const int wv = t >> 6;
  const int n0 = blockIdx.x * 64;

  f32x4_t ofrag[4];
#pragma unroll
  for (int ct = 0; ct < 4; ++ct) ofrag[ct] = (f32x4_t){0.f, 0.f, 0.f, 0.f};
  float b1v[4], bcv[4];
#pragma unroll
  for (int ct = 0; ct < 4; ++ct) {
    b1v[ct] = b1[ct * 16 + (lane & 15)];
    bcv[ct] = bc[ct * 16 + (lane & 15)];
  }

#define LOAD_TILE_F32(SRC)                                                    \
  {                                                                           \
    const int r = t >> 2;                                                     \
    const int cb = (t & 3) * 16;                                              \
    const int n = n0 + r;                                                     \
    _Pragma("unroll") for (int ii = 0; ii < 4; ++ii) {                        \
      float4 v = make_float4(0.f, 0.f, 0.f, 0.f);                             \
      if (n < NN)                                                             \
        v = *reinterpret_cast<const float4*>((SRC) + (size_t)n * DD + cb +    \
                                             ii * 4);                         \
      *reinterpret_cast<float4*>(&TA[r * TSTR + cb + ii * 4]) = v;            \
    }                                                                         \
  }

#define H_PASS(MATW1)                                                         \
  {                                                                           \
    f32x4_t h[4];                                                             \
    _Pragma("unroll") for (int ct = 0; ct < 4; ++ct) h[ct] =                  \
        (f32x4_t){0.f, 0.f, 0.f, 0.f};                                        \
    mm_pass(TA, wv, lane, whi, wlo, (MATW1), h);                              \
    _Pragma("unroll") for (int ct = 0; ct < 4; ++ct)                          \
        _Pragma("unroll") for (int r = 0; r < 4; ++r) {                       \
      const float hv = fmaxf(h[ct][r] + b1v[ct], 0.f);                        \
      TH[((wv << 4) + ((lane >> 4) << 2) + r) * TSTR + ct * 16 +              \
         (lane & 15)] = hv;                                                   \
    }                                                                         \
  }

  LOAD_TILE_F32(agg_in);
  __syncthreads();
  H_PASS(0);
  __syncthreads();
  mm_pass(TH, wv, lane, whi, wlo, 1, ofrag);
  __syncthreads();
  LOAD_TILE_F32(agg_out);
  __syncthreads();
  H_PASS(0);
  __syncthreads();
  mm_pass(TH, wv, lane, whi, wlo, 2, ofrag);
  __syncthreads();
  LOAD_TILE_F32(x);
  __syncthreads();
  mm_pass(TA, wv, lane, whi, wlo, 3, ofrag);

#pragma unroll
  for (int ct = 0; ct < 4; ++ct)
#pragma unroll
    for (int r = 0; r < 4; ++r) {
      const int n = n0 + (wv << 4) + ((lane >> 4) << 2) + r;
      if (n < NN)
        out[(size_t)n * DD + ct * 16 + (lane & 15)] = ofrag[ct][r] + bcv[ct];
    }
}

extern "C" void kernel_launch(void* const* d_in, const int* in_sizes, int n_in,
                              void* d_out, int out_size, void* d_ws,
                              size_t ws_size, hipStream_t stream) {
  const float* x = (const float*)d_in[0];
  const int* ei = (const int*)d_in[1];
  const float* ea = (const float*)d_in[2];
  const float* W1 = (const float*)d_in[3];
  const float* b1 = (const float*)d_in[4];
  const float* W2 = (const float*)d_in[5];
  const float* b2 = (const float*)d_in[6];
  const float* Wl = (const float*)d_in[7];
  const float* bl = (const float*)d_in[8];
  float* out = (float*)d_out;
  float* ws = (float*)d_ws;

  // layout (16B-aligned segments)
  float* agg_in = ws;                               // NN*DD f32
  float* agg_out = agg_in + (size_t)NN * DD;        // NN*DD f32
  int* tmp = (int*)(agg_out + (size_t)NN * DD);     // 2*NE ints (10 MB)
  int* bcnt = tmp + 2 * (size_t)NE;                 // NCNT2 ints
  int* bbase = bcnt + NCNT2 + 2;                    // NCNT2+8
  int* bcur2 = bbase + NCNT2 + 8;                   // NCNT2 (+pad)
  float* Wc1 = (float*)(bcur2 + NCNT2 + 8);
  float* Wc2 = Wc1 + 4096;
  float* bc = Wc2 + 4096;
  unsigned short* whi = (unsigned short*)(bc + 64);  // 4*4096 bf16
  unsigned short* wlo = whi + 4 * 4096;              // 4*4096 bf16
  const size_t need = (size_t)((char*)(wlo + 4 * 4096) - (char*)ws);  // ~61.5MB

  const bool bkt_ok = ws_size >= need;
  if (!bkt_ok) {
    Wc1 = agg_out + (size_t)NN * DD;
    Wc2 = Wc1 + 4096;
    bc = Wc2 + 4096;
    whi = (unsigned short*)(bc + 64);
    wlo = whi + 4 * 4096;
  }

  precompute_kernel<<<32, 256, 0, stream>>>(W2, b2, Wl, bl, Wc1, Wc2, bc);
  pack_w_kernel<<<64, 256, 0, stream>>>(W1, Wl, Wc1, Wc2, whi, wlo);

  if (bkt_ok) {
    hipMemsetAsync(bcnt, 0, NCNT2 * sizeof(int), stream);
    bucket_hist_kernel<<<HBLK, 256, 0, stream>>>(ei, bcnt);
    bucket_scan_kernel<<<1, 1024, 0, stream>>>(bcnt, bbase, bcur2);
    multisplit_kernel<<<2 * NCHUNK, 256, 0, stream>>>(ei, bcur2, tmp);
    sort_gather_kernel<<<2 * NBKT, 512, 0, stream>>>(x, ea, ei, tmp, bbase,
                                                     agg_in, agg_out);
  } else {
    hipMemsetAsync(agg_in, 0, 2 * (size_t)NN * DD * sizeof(float), stream);
    edge_kernel<<<((size_t)NE * 16 + 255) / 256, 256, 0, stream>>>(
        x, ei, ea, agg_in, agg_out);
  }

  node_kernel<<<(NN + 63) / 64, 256, 0, stream>>>(x, agg_in, agg_out, b1, bc,
                                                  whi, wlo, out);
}

// Round 13
// 329.374 us; speedup vs baseline: 1.0743x; 1.0743x over previous
//
#include <hip/hip_runtime.h>

#define NN 100000
#define NE 1250000
#define DD 64
#define NBKT 391            // buckets of 256 nodes: 391*256 = 100096 >= NN
#define NCNT NBKT           // counters per direction
#define NCNT2 (2 * NCNT)    // 782
#define CHUNK 8192
#define NCHUNK ((NE + CHUNK - 1) / CHUNK)  // 153
#define SORT_CAP 4096       // fixed region capacity per (bucket,dir); mean 3196
#define GNB 25000           // gather node-blocks per direction (4 nodes/block)
#define TSTR 68             // node-kernel LDS tile stride (f32), pad 4

typedef __attribute__((ext_vector_type(8))) short bf16x8_t;
typedef __attribute__((ext_vector_type(4))) float f32x4_t;

__device__ __forceinline__ unsigned short bf16_rne(float v) {
  unsigned u = __builtin_bit_cast(unsigned, v);
  u += 0x7FFFu + ((u >> 16) & 1u);
  return (unsigned short)(u >> 16);
}
__device__ __forceinline__ void split_bf16(float v, unsigned short& hi,
                                           unsigned short& lo) {
  hi = bf16_rne(v);
  const float fh = __builtin_bit_cast(float, ((unsigned)hi) << 16);
  lo = bf16_rne(v - fh);
}

// ---------------- precompute: Wc1 = W2 @ Wl[64:128], Wc2 = W2 @ Wl[128:192],
// ----------------             bc = b_lin + b2 @ (Wl[64:128] + Wl[128:192])
__global__ __launch_bounds__(256) void precompute_kernel(
    const float* __restrict__ W2, const float* __restrict__ b2,
    const float* __restrict__ Wl, const float* __restrict__ bl,
    float* __restrict__ Wc1, float* __restrict__ Wc2, float* __restrict__ bc) {
  const int t = blockIdx.x * 256 + threadIdx.x;  // 32 blocks x 256 = 8192
  const int m = t >> 12;                         // 0 -> Wc1, 1 -> Wc2
  const int ij = t & 4095;
  const int i = ij >> 6, j = ij & 63;
  const float* Wp = Wl + (m ? 128 : 64) * 64;
  float s = 0.f;
#pragma unroll 8
  for (int k = 0; k < 64; ++k) s = fmaf(W2[i * 64 + k], Wp[k * 64 + j], s);
  if (m) Wc2[ij] = s; else Wc1[ij] = s;
  if (t < 64) {
    float sb = bl[t];
    for (int k = 0; k < 64; ++k)
      sb = fmaf(b2[k], Wl[(64 + k) * 64 + t] + Wl[(128 + k) * 64 + t], sb);
    bc[t] = sb;
  }
}

// ---------------- pack weights into MFMA B-fragment order (hi/lo bf16) -----
__global__ __launch_bounds__(256) void pack_w_kernel(
    const float* __restrict__ W1, const float* __restrict__ Wl,
    const float* __restrict__ Wc1, const float* __restrict__ Wc2,
    unsigned short* __restrict__ whi, unsigned short* __restrict__ wlo) {
  const int g = blockIdx.x * 256 + threadIdx.x;
  if (g >= 4 * 4096) return;
  const int mat = g >> 12;
  const int idx = g & 4095;
  const int i = idx & 7;
  const int lane = (idx >> 3) & 63;
  const int ct = (idx >> 9) & 3;
  const int ks = (idx >> 11) & 1;
  const int k = ks * 32 + ((lane >> 4) << 2) + (i & 3) + ((i >> 2) << 4);
  const int col = ct * 16 + (lane & 15);
  const float* src = (mat == 0) ? W1 : (mat == 1) ? Wc1 : (mat == 2) ? Wc2 : Wl;
  const float v = src[k * 64 + col];
  unsigned short h, l;
  split_bf16(v, h, l);
  whi[g] = h;
  wlo[g] = l;
}

// ---------------- multisplit scatter into fixed-capacity bucket regions ----
// record: (e << 8) | key_in_bucket  (e < 2^21, key < 256 -> 29 bits)
// region base for (bucket b, dir) = (dir*NBKT + b) * SORT_CAP; bcur2 counts.
__global__ __launch_bounds__(256) void multisplit_kernel(
    const int* __restrict__ ei, int* __restrict__ bcur2,
    int* __restrict__ tmp) {
  __shared__ int recs[CHUNK];       // 32 KB
  __shared__ int hist[NBKT];
  __shared__ int hbase[NBKT + 1];
  __shared__ int hcur[NBKT];
  __shared__ int gbase[NBKT];
  __shared__ int scanbuf[256];
  const int t = threadIdx.x;
  const int dir = (blockIdx.x >= NCHUNK) ? 1 : 0;
  const int chunk = blockIdx.x - (dir ? NCHUNK : 0);
  const int e0 = chunk * CHUNK;
  const int cnt = min(CHUNK, NE - e0);
  const int* keys = ei + (dir ? 0 : NE);  // dir0: key=dst; dir1: key=src
  for (int i = t; i < NBKT; i += 256) {
    hist[i] = 0;
    hcur[i] = 0;
  }
  __syncthreads();
  for (int i = t; i < cnt; i += 256) atomicAdd(&hist[keys[e0 + i] >> 8], 1);
  __syncthreads();
  const int i0 = 2 * t, i1 = 2 * t + 1;
  const int s0 = (i0 < NBKT) ? hist[i0] : 0;
  const int s1 = (i1 < NBKT) ? hist[i1] : 0;
  const int ps = s0 + s1;
  scanbuf[t] = ps;
  __syncthreads();
  int acc = ps;
  for (int d = 1; d < 256; d <<= 1) {
    const int add = (t >= d) ? scanbuf[t - d] : 0;
    __syncthreads();
    acc += add;
    scanbuf[t] = acc;
    __syncthreads();
  }
  const int pre = acc - ps;
  if (i0 < NBKT) hbase[i0] = pre;
  if (i1 < NBKT) hbase[i1] = pre + s0;
  if (t == 0) hbase[NBKT] = cnt;
  __syncthreads();
  for (int b = t; b < NBKT; b += 256) {
    const int c = hist[b];
    if (c > 0)
      gbase[b] = (dir * NBKT + b) * SORT_CAP +
                 atomicAdd(&bcur2[dir * NBKT + b], c);
  }
  for (int i = t; i < cnt; i += 256) {
    const int n = keys[e0 + i];
    const int b = n >> 8;
    const int p = hbase[b] + atomicAdd(&hcur[b], 1);
    recs[p] = ((e0 + i) << 8) | (n & 255);
  }
  __syncthreads();
  for (int p = t; p < cnt; p += 256) {
    int lo = 0, hi = NBKT;
    while (hi - lo > 1) {
      const int mid = (lo + hi) >> 1;
      if (hbase[mid] <= p) lo = mid;
      else hi = mid;
    }
    tmp[gbase[lo] + (p - hbase[lo])] = recs[p];
  }
}

// per-(bucket,direction) block: counting sort -> offb/offe[] + lst2[(e,partner)]
__global__ __launch_bounds__(256) void bucket_sort_kernel(
    const int* __restrict__ tmp, const int* __restrict__ bcur2,
    const int* __restrict__ ei, int* __restrict__ offb_d,
    int* __restrict__ offe_d, int* __restrict__ offb_s,
    int* __restrict__ offe_s, int2* __restrict__ lst2) {
  __shared__ int hist[256];
  __shared__ int scanbuf[256];
  __shared__ int cur[256];
  const int t = threadIdx.x;
  const int isrc = (blockIdx.x >= NBKT) ? 1 : 0;
  const int bloc = blockIdx.x - (isrc ? NBKT : 0);
  const int base = (isrc * NBKT + bloc) * SORT_CAP;
  const int cnt = min(bcur2[isrc * NCNT + bloc], SORT_CAP);
  const int* pbase = ei + (isrc ? NE : 0);  // partner array for this dir
  hist[t] = 0;
  __syncthreads();
  for (int k = t; k < cnt; k += 256) atomicAdd(&hist[tmp[base + k] & 255], 1);
  __syncthreads();
  const int v = hist[t];
  int acc = v;
  scanbuf[t] = v;
  __syncthreads();
  for (int d = 1; d < 256; d <<= 1) {
    const int add = (t >= d) ? scanbuf[t - d] : 0;
    __syncthreads();
    acc += add;
    scanbuf[t] = acc;
    __syncthreads();
  }
  const int beg_t = base + acc - v;  // exclusive
  cur[t] = beg_t;
  int* offb = isrc ? offb_s : offb_d;
  int* offe = isrc ? offe_s : offe_d;
  const int n = bloc * 256 + t;
  if (n < NN) {
    offb[n] = beg_t;
    offe[n] = base + acc;
  }
  __syncthreads();
  for (int k = t; k < cnt; k += 256) {
    const int r = tmp[base + k];
    const int e = (int)(((unsigned)r) >> 8);
    const int p = atomicAdd(&cur[r & 255], 1);
    lst2[p] = make_int2(e, pbase[e]);
  }
}

// ---------------- gather: agg[n] = sum_e relu(x[partner] + ea[e]) ----------
// One 64-lane wave per node: 8 edge-slots x 8 lanes; 2 float4 per lane.
__global__ __launch_bounds__(256) void gather_kernel(
    const float* __restrict__ x, const float* __restrict__ ea,
    const int* __restrict__ offb_d, const int* __restrict__ offe_d,
    const int* __restrict__ offb_s, const int* __restrict__ offe_s,
    const int2* __restrict__ lst2, float* __restrict__ agg_in,
    float* __restrict__ agg_out) {
  const int t = threadIdx.x;
  const int wave = t >> 6;
  const int lane = t & 63;
  const int slot = lane >> 3;  // 8 slots
  const int q = lane & 7;      // 8 lanes per slot
  const int dir = (blockIdx.x >= GNB) ? 1 : 0;
  const int n = (blockIdx.x - (dir ? GNB : 0)) * 4 + wave;
  if (n >= NN) return;
  const int* offb = dir ? offb_s : offb_d;
  const int* offe = dir ? offe_s : offe_d;
  float* agg = dir ? agg_out : agg_in;
  const int beg = offb[n];
  const int end = offe[n];
  const int c0 = q * 8;  // floats [c0, c0+8)
  float4 acc0 = make_float4(0.f, 0.f, 0.f, 0.f);
  float4 acc1 = make_float4(0.f, 0.f, 0.f, 0.f);
  for (int k = beg + slot; k < end; k += 8) {
    const int2 r = lst2[k];
    const float* ar = ea + (size_t)r.x * DD + c0;
    const float* xr = x + (size_t)r.y * DD + c0;
    const float4 a0 = *reinterpret_cast<const float4*>(ar);
    const float4 a1 = *reinterpret_cast<const float4*>(ar + 4);
    const float4 x0 = *reinterpret_cast<const float4*>(xr);
    const float4 x1 = *reinterpret_cast<const float4*>(xr + 4);
    acc0.x += fmaxf(a0.x + x0.x, 0.f);
    acc0.y += fmaxf(a0.y + x0.y, 0.f);
    acc0.z += fmaxf(a0.z + x0.z, 0.f);
    acc0.w += fmaxf(a0.w + x0.w, 0.f);
    acc1.x += fmaxf(a1.x + x1.x, 0.f);
    acc1.y += fmaxf(a1.y + x1.y, 0.f);
    acc1.z += fmaxf(a1.z + x1.z, 0.f);
    acc1.w += fmaxf(a1.w + x1.w, 0.f);
  }
#pragma unroll
  for (int m = 8; m <= 32; m <<= 1) {
    acc0.x += __shfl_xor(acc0.x, m);
    acc0.y += __shfl_xor(acc0.y, m);
    acc0.z += __shfl_xor(acc0.z, m);
    acc0.w += __shfl_xor(acc0.w, m);
    acc1.x += __shfl_xor(acc1.x, m);
    acc1.y += __shfl_xor(acc1.y, m);
    acc1.z += __shfl_xor(acc1.z, m);
    acc1.w += __shfl_xor(acc1.w, m);
  }
  if (lane < 8) {
    float* p = agg + (size_t)n * DD + lane * 8;
    *reinterpret_cast<float4*>(p) = acc0;
    *reinterpret_cast<float4*>(p + 4) = acc1;
  }
}

// ---------------- fallback edge pass (atomic) if ws too small -------------
__global__ __launch_bounds__(256) void edge_kernel(
    const float* __restrict__ x, const int* __restrict__ ei,
    const float* __restrict__ ea, float* __restrict__ agg_in,
    float* __restrict__ agg_out) {
  const int tid = blockIdx.x * 256 + threadIdx.x;
  const int e = tid >> 4;
  if (e >= NE) return;
  const int c = (tid & 15) * 4;
  const int s = ei[e];
  const int d = ei[NE + e];
  const float4 a = *reinterpret_cast<const float4*>(ea + (size_t)e * DD + c);
  const float4 xs = *reinterpret_cast<const float4*>(x + (size_t)s * DD + c);
  const float4 xd = *reinterpret_cast<const float4*>(x + (size_t)d * DD + c);
  float* pi = agg_in + (size_t)d * DD + c;
  unsafeAtomicAdd(pi + 0, fmaxf(xs.x + a.x, 0.f));
  unsafeAtomicAdd(pi + 1, fmaxf(xs.y + a.y, 0.f));
  unsafeAtomicAdd(pi + 2, fmaxf(xs.z + a.z, 0.f));
  unsafeAtomicAdd(pi + 3, fmaxf(xs.w + a.w, 0.f));
  float* po = agg_out + (size_t)s * DD + c;
  unsafeAtomicAdd(po + 0, fmaxf(xd.x + a.x, 0.f));
  unsafeAtomicAdd(po + 1, fmaxf(xd.y + a.y, 0.f));
  unsafeAtomicAdd(po + 2, fmaxf(xd.z + a.z, 0.f));
  unsafeAtomicAdd(po + 3, fmaxf(xd.w + a.w, 0.f));
}

// ---------------- MFMA node MLP + final projection ----------------
__device__ __forceinline__ void mm_pass(const float* At, int wv, int lane,
                                        const unsigned short* __restrict__ whi,
                                        const unsigned short* __restrict__ wlo,
                                        int mat, f32x4_t acc[4]) {
  const int row = (wv << 4) + (lane & 15);
  const int kbase = ((lane >> 4) & 3) << 2;
#pragma unroll
  for (int ks = 0; ks < 2; ++ks) {
    const float* ap = At + row * TSTR + ks * 32 + kbase;
    const float4 g0 = *reinterpret_cast<const float4*>(ap);
    const float4 g1 = *reinterpret_cast<const float4*>(ap + 16);
    const float gv[8] = {g0.x, g0.y, g0.z, g0.w, g1.x, g1.y, g1.z, g1.w};
    bf16x8_t ahi, alo;
#pragma unroll
    for (int i = 0; i < 8; ++i) {
      unsigned short h, l;
      split_bf16(gv[i], h, l);
      ahi[i] = (short)h;
      alo[i] = (short)l;
    }
#pragma unroll
    for (int ct = 0; ct < 4; ++ct) {
      const int fb = ((mat * 2 + ks) * 4 + ct) * 512 + lane * 8;
      const bf16x8_t wh = *reinterpret_cast<const bf16x8_t*>(whi + fb);
      const bf16x8_t wl = *reinterpret_cast<const bf16x8_t*>(wlo + fb);
      acc[ct] = __builtin_amdgcn_mfma_f32_16x16x32_bf16(ahi, wh, acc[ct], 0, 0, 0);
      acc[ct] = __builtin_amdgcn_mfma_f32_16x16x32_bf16(alo, wh, acc[ct], 0, 0, 0);
      acc[ct] = __builtin_amdgcn_mfma_f32_16x16x32_bf16(ahi, wl, acc[ct], 0, 0, 0);
    }
  }
}

__global__ __launch_bounds__(256) void node_kernel(
    const float* __restrict__ x, const float* __restrict__ agg_in,
    const float* __restrict__ agg_out, const float* __restrict__ b1,
    const float* __restrict__ bc, const unsigned short* __restrict__ whi,
    const unsigned short* __restrict__ wlo, float* __restrict__ out) {
  __shared__ float TA[64 * TSTR];
  __shared__ float TH[64 * TSTR];
  const int t = threadIdx.x;
  const int lane = t & 63;
  const int wv = t >> 6;
  const int n0 = blockIdx.x * 64;

  f32x4_t ofrag[4];
#pragma unroll
  for (int ct = 0; ct < 4; ++ct) ofrag[ct] = (f32x4_t){0.f, 0.f, 0.f, 0.f};
  float b1v[4], bcv[4];
#pragma unroll
  for (int ct = 0; ct < 4; ++ct) {
    b1v[ct] = b1[ct * 16 + (lane & 15)];
    bcv[ct] = bc[ct * 16 + (lane & 15)];
  }

#define LOAD_TILE_F32(SRC)                                                    \
  {                                                                           \
    const int r = t >> 2;                                                     \
    const int cb = (t & 3) * 16;                                              \
    const int n = n0 + r;                                                     \
    _Pragma("unroll") for (int ii = 0; ii < 4; ++ii) {                        \
      float4 v = make_float4(0.f, 0.f, 0.f, 0.f);                             \
      if (n < NN)                                                             \
        v = *reinterpret_cast<const float4*>((SRC) + (size_t)n * DD + cb +    \
                                             ii * 4);                         \
      *reinterpret_cast<float4*>(&TA[r * TSTR + cb + ii * 4]) = v;            \
    }                                                                         \
  }

#define H_PASS(MATW1)                                                         \
  {                                                                           \
    f32x4_t h[4];                                                             \
    _Pragma("unroll") for (int ct = 0; ct < 4; ++ct) h[ct] =                  \
        (f32x4_t){0.f, 0.f, 0.f, 0.f};                                        \
    mm_pass(TA, wv, lane, whi, wlo, (MATW1), h);                              \
    _Pragma("unroll") for (int ct = 0; ct < 4; ++ct)                          \
        _Pragma("unroll") for (int r = 0; r < 4; ++r) {                       \
      const float hv = fmaxf(h[ct][r] + b1v[ct], 0.f);                        \
      TH[((wv << 4) + ((lane >> 4) << 2) + r) * TSTR + ct * 16 +              \
         (lane & 15)] = hv;                                                   \
    }                                                                         \
  }

  LOAD_TILE_F32(agg_in);
  __syncthreads();
  H_PASS(0);
  __syncthreads();
  mm_pass(TH, wv, lane, whi, wlo, 1, ofrag);
  __syncthreads();
  LOAD_TILE_F32(agg_out);
  __syncthreads();
  H_PASS(0);
  __syncthreads();
  mm_pass(TH, wv, lane, whi, wlo, 2, ofrag);
  __syncthreads();
  LOAD_TILE_F32(x);
  __syncthreads();
  mm_pass(TA, wv, lane, whi, wlo, 3, ofrag);

#pragma unroll
  for (int ct = 0; ct < 4; ++ct)
#pragma unroll
    for (int r = 0; r < 4; ++r) {
      const int n = n0 + (wv << 4) + ((lane >> 4) << 2) + r;
      if (n < NN)
        out[(size_t)n * DD + ct * 16 + (lane & 15)] = ofrag[ct][r] + bcv[ct];
    }
}

extern "C" void kernel_launch(void* const* d_in, const int* in_sizes, int n_in,
                              void* d_out, int out_size, void* d_ws,
                              size_t ws_size, hipStream_t stream) {
  const float* x = (const float*)d_in[0];
  const int* ei = (const int*)d_in[1];
  const float* ea = (const float*)d_in[2];
  const float* W1 = (const float*)d_in[3];
  const float* b1 = (const float*)d_in[4];
  const float* W2 = (const float*)d_in[5];
  const float* b2 = (const float*)d_in[6];
  const float* Wl = (const float*)d_in[7];
  const float* bl = (const float*)d_in[8];
  float* out = (float*)d_out;
  float* ws = (float*)d_ws;

  const size_t REG = (size_t)NCNT2 * SORT_CAP;      // 3,203,072 records
  // layout (16B-aligned segments)
  float* agg_in = ws;                               // NN*DD f32
  float* agg_out = agg_in + (size_t)NN * DD;        // NN*DD f32
  int* tmp = (int*)(agg_out + (size_t)NN * DD);     // REG ints (12.8 MB)
  int2* lst2 = (int2*)(tmp + REG);                  // REG int2 (25.6 MB)
  int* offb_d = (int*)(lst2 + REG);                 // NN+4
  int* offe_d = offb_d + NN + 4;                    // NN+4
  int* offb_s = offe_d + NN + 4;                    // NN+4
  int* offe_s = offb_s + NN + 4;                    // NN+4
  int* bcur2 = offe_s + NN + 4;                     // NCNT2 (+pad)
  float* Wc1 = (float*)(bcur2 + NCNT2 + 10);
  float* Wc2 = Wc1 + 4096;
  float* bc = Wc2 + 4096;
  unsigned short* whi = (unsigned short*)(bc + 64);  // 4*4096 bf16
  unsigned short* wlo = whi + 4 * 4096;              // 4*4096 bf16
  const size_t need = (size_t)((char*)(wlo + 4 * 4096) - (char*)ws);  // ~92 MB

  const bool bkt_ok = ws_size >= need;
  if (!bkt_ok) {
    Wc1 = agg_out + (size_t)NN * DD;
    Wc2 = Wc1 + 4096;
    bc = Wc2 + 4096;
    whi = (unsigned short*)(bc + 64);
    wlo = whi + 4 * 4096;
  }

  precompute_kernel<<<32, 256, 0, stream>>>(W2, b2, Wl, bl, Wc1, Wc2, bc);
  pack_w_kernel<<<64, 256, 0, stream>>>(W1, Wl, Wc1, Wc2, whi, wlo);

  if (bkt_ok) {
    hipMemsetAsync(bcur2, 0, NCNT2 * sizeof(int), stream);
    multisplit_kernel<<<2 * NCHUNK, 256, 0, stream>>>(ei, bcur2, tmp);
    bucket_sort_kernel<<<2 * NBKT, 256, 0, stream>>>(
        tmp, bcur2, ei, offb_d, offe_d, offb_s, offe_s, lst2);
    gather_kernel<<<2 * GNB, 256, 0, stream>>>(x, ea, offb_d, offe_d, offb_s,
                                               offe_s, lst2, agg_in, agg_out);
  } else {
    hipMemsetAsync(agg_in, 0, 2 * (size_t)NN * DD * sizeof(float), stream);
    edge_kernel<<<((size_t)NE * 16 + 255) / 256, 256, 0, stream>>>(
        x, ei, ea, agg_in, agg_out);
  }

  node_kernel<<<(NN + 63) / 64, 256, 0, stream>>>(x, agg_in, agg_out, b1, bc,
                                                  whi, wlo, out);
}

// Round 14
// 288.394 us; speedup vs baseline: 1.2269x; 1.1421x over previous
//
#include <hip/hip_runtime.h>

#define NN 100000
#define NE 1250000
#define DD 64
#define NBKT 391            // buckets of 256 nodes: 391*256 = 100096 >= NN
#define NCNT NBKT           // counters per direction
#define NCNT2 (2 * NCNT)    // 782
#define CHUNK 4096
#define NCHUNK ((NE + CHUNK - 1) / CHUNK)  // 306
#define SORT_CAP 4096       // fixed region capacity per (bucket,dir); mean 3196
#define GNB 25000           // gather node-blocks per direction (4 nodes/block)
#define TSTR 68             // node-kernel LDS tile stride (f32), pad 4

typedef __attribute__((ext_vector_type(8))) short bf16x8_t;
typedef __attribute__((ext_vector_type(4))) float f32x4_t;

__device__ __forceinline__ unsigned short bf16_rne(float v) {
  unsigned u = __builtin_bit_cast(unsigned, v);
  u += 0x7FFFu + ((u >> 16) & 1u);
  return (unsigned short)(u >> 16);
}
__device__ __forceinline__ void split_bf16(float v, unsigned short& hi,
                                           unsigned short& lo) {
  hi = bf16_rne(v);
  const float fh = __builtin_bit_cast(float, ((unsigned)hi) << 16);
  lo = bf16_rne(v - fh);
}

// ---------------- precompute: Wc1 = W2 @ Wl[64:128], Wc2 = W2 @ Wl[128:192],
// ----------------             bc = b_lin + b2 @ (Wl[64:128] + Wl[128:192])
__global__ __launch_bounds__(256) void precompute_kernel(
    const float* __restrict__ W2, const float* __restrict__ b2,
    const float* __restrict__ Wl, const float* __restrict__ bl,
    float* __restrict__ Wc1, float* __restrict__ Wc2, float* __restrict__ bc) {
  const int t = blockIdx.x * 256 + threadIdx.x;  // 32 blocks x 256 = 8192
  const int m = t >> 12;                         // 0 -> Wc1, 1 -> Wc2
  const int ij = t & 4095;
  const int i = ij >> 6, j = ij & 63;
  const float* Wp = Wl + (m ? 128 : 64) * 64;
  float s = 0.f;
#pragma unroll 8
  for (int k = 0; k < 64; ++k) s = fmaf(W2[i * 64 + k], Wp[k * 64 + j], s);
  if (m) Wc2[ij] = s; else Wc1[ij] = s;
  if (t < 64) {
    float sb = bl[t];
    for (int k = 0; k < 64; ++k)
      sb = fmaf(b2[k], Wl[(64 + k) * 64 + t] + Wl[(128 + k) * 64 + t], sb);
    bc[t] = sb;
  }
}

// ---------------- pack weights into MFMA B-fragment order (hi/lo bf16) -----
__global__ __launch_bounds__(256) void pack_w_kernel(
    const float* __restrict__ W1, const float* __restrict__ Wl,
    const float* __restrict__ Wc1, const float* __restrict__ Wc2,
    unsigned short* __restrict__ whi, unsigned short* __restrict__ wlo) {
  const int g = blockIdx.x * 256 + threadIdx.x;
  if (g >= 4 * 4096) return;
  const int mat = g >> 12;
  const int idx = g & 4095;
  const int i = idx & 7;
  const int lane = (idx >> 3) & 63;
  const int ct = (idx >> 9) & 3;
  const int ks = (idx >> 11) & 1;
  const int k = ks * 32 + ((lane >> 4) << 2) + (i & 3) + ((i >> 2) << 4);
  const int col = ct * 16 + (lane & 15);
  const float* src = (mat == 0) ? W1 : (mat == 1) ? Wc1 : (mat == 2) ? Wc2 : Wl;
  const float v = src[k * 64 + col];
  unsigned short h, l;
  split_bf16(v, h, l);
  whi[g] = h;
  wlo[g] = l;
}

// ---------------- multisplit scatter into fixed-capacity bucket regions ----
// record: int2 (e, partner<<8 | key). region base = (dir*NBKT+b)*SORT_CAP.
// bucket id per staged position kept in rbkt[] -> no binary search on writeout.
__global__ __launch_bounds__(256) void multisplit_kernel(
    const int* __restrict__ ei, int* __restrict__ bcur2,
    int2* __restrict__ tmp) {
  __shared__ int2 recs[CHUNK];            // 32 KB
  __shared__ unsigned short rbkt[CHUNK];  // 8 KB
  __shared__ int hist[NBKT];
  __shared__ int hbase[NBKT];
  __shared__ int hcur[NBKT];
  __shared__ int gbase[NBKT];
  __shared__ int scanbuf[256];
  const int t = threadIdx.x;
  const int dir = (blockIdx.x >= NCHUNK) ? 1 : 0;
  const int chunk = blockIdx.x - (dir ? NCHUNK : 0);
  const int e0 = chunk * CHUNK;
  const int cnt = min(CHUNK, NE - e0);
  const int* keys = ei + (dir ? 0 : NE);  // dir0: key=dst; dir1: key=src
  const int* prt = ei + (dir ? NE : 0);   // partner array for this dir
  for (int i = t; i < NBKT; i += 256) {
    hist[i] = 0;
    hcur[i] = 0;
  }
  __syncthreads();
  for (int i = t; i < cnt; i += 256) atomicAdd(&hist[keys[e0 + i] >> 8], 1);
  __syncthreads();
  const int i0 = 2 * t, i1 = 2 * t + 1;
  const int s0 = (i0 < NBKT) ? hist[i0] : 0;
  const int s1 = (i1 < NBKT) ? hist[i1] : 0;
  const int ps = s0 + s1;
  scanbuf[t] = ps;
  __syncthreads();
  int acc = ps;
  for (int d = 1; d < 256; d <<= 1) {
    const int add = (t >= d) ? scanbuf[t - d] : 0;
    __syncthreads();
    acc += add;
    scanbuf[t] = acc;
    __syncthreads();
  }
  const int pre = acc - ps;
  if (i0 < NBKT) hbase[i0] = pre;
  if (i1 < NBKT) hbase[i1] = pre + s0;
  __syncthreads();
  for (int b = t; b < NBKT; b += 256) {
    const int c = hist[b];
    if (c > 0)
      gbase[b] = (dir * NBKT + b) * SORT_CAP +
                 atomicAdd(&bcur2[dir * NBKT + b], c);
  }
  for (int i = t; i < cnt; i += 256) {
    const int n = keys[e0 + i];
    const int b = n >> 8;
    const int p = hbase[b] + atomicAdd(&hcur[b], 1);
    recs[p] = make_int2(e0 + i, (prt[e0 + i] << 8) | (n & 255));
    rbkt[p] = (unsigned short)b;
  }
  __syncthreads();
  for (int p = t; p < cnt; p += 256) {
    const int b = rbkt[p];
    tmp[gbase[b] + (p - hbase[b])] = recs[p];
  }
}

// per-(bucket,direction) block: counting sort (streaming only) ->
// offb/offe[] + lst2[(e, partner)]
__global__ __launch_bounds__(512) void bucket_sort_kernel(
    const int2* __restrict__ tmp, const int* __restrict__ bcur2,
    int* __restrict__ offb_d, int* __restrict__ offe_d,
    int* __restrict__ offb_s, int* __restrict__ offe_s,
    int2* __restrict__ lst2) {
  __shared__ int hist[256];
  __shared__ int scanbuf[256];
  __shared__ int cur[256];
  const int t = threadIdx.x;
  const int isrc = (blockIdx.x >= NBKT) ? 1 : 0;
  const int bloc = blockIdx.x - (isrc ? NBKT : 0);
  const int base = (isrc * NBKT + bloc) * SORT_CAP;
  const int cnt = min(bcur2[isrc * NCNT + bloc], SORT_CAP);
  if (t < 256) hist[t] = 0;
  __syncthreads();
  for (int k = t; k < cnt; k += 512)
    atomicAdd(&hist[tmp[base + k].y & 255], 1);
  __syncthreads();
  int v = 0, acc = 0;
  if (t < 256) {
    v = hist[t];
    acc = v;
    scanbuf[t] = v;
  }
  __syncthreads();
  for (int d = 1; d < 256; d <<= 1) {
    int add = 0;
    if (t < 256 && t >= d) add = scanbuf[t - d];
    __syncthreads();
    if (t < 256) {
      acc += add;
      scanbuf[t] = acc;
    }
    __syncthreads();
  }
  if (t < 256) {
    cur[t] = base + acc - v;
    int* offb = isrc ? offb_s : offb_d;
    int* offe = isrc ? offe_s : offe_d;
    const int n = bloc * 256 + t;
    if (n < NN) {
      offb[n] = base + acc - v;
      offe[n] = base + acc;
    }
  }
  __syncthreads();
  for (int k = t; k < cnt; k += 512) {
    const int2 r = tmp[base + k];
    const int p = atomicAdd(&cur[r.y & 255], 1);
    lst2[p] = make_int2(r.x, (int)(((unsigned)r.y) >> 8));
  }
}

// ---------------- gather: agg[n] = sum_e relu(x[partner] + ea[e]) ----------
// One 64-lane wave per node: 8 edge-slots x 8 lanes; 2 float4 per lane.
__global__ __launch_bounds__(256) void gather_kernel(
    const float* __restrict__ x, const float* __restrict__ ea,
    const int* __restrict__ offb_d, const int* __restrict__ offe_d,
    const int* __restrict__ offb_s, const int* __restrict__ offe_s,
    const int2* __restrict__ lst2, float* __restrict__ agg_in,
    float* __restrict__ agg_out) {
  const int t = threadIdx.x;
  const int wave = t >> 6;
  const int lane = t & 63;
  const int slot = lane >> 3;  // 8 slots
  const int q = lane & 7;      // 8 lanes per slot
  const int dir = (blockIdx.x >= GNB) ? 1 : 0;
  const int n = (blockIdx.x - (dir ? GNB : 0)) * 4 + wave;
  if (n >= NN) return;
  const int* offb = dir ? offb_s : offb_d;
  const int* offe = dir ? offe_s : offe_d;
  float* agg = dir ? agg_out : agg_in;
  const int beg = offb[n];
  const int end = offe[n];
  const int c0 = q * 8;  // floats [c0, c0+8)
  float4 acc0 = make_float4(0.f, 0.f, 0.f, 0.f);
  float4 acc1 = make_float4(0.f, 0.f, 0.f, 0.f);
  for (int k = beg + slot; k < end; k += 8) {
    const int2 r = lst2[k];
    const float* ar = ea + (size_t)r.x * DD + c0;
    const float* xr = x + (size_t)r.y * DD + c0;
    const float4 a0 = *reinterpret_cast<const float4*>(ar);
    const float4 a1 = *reinterpret_cast<const float4*>(ar + 4);
    const float4 x0 = *reinterpret_cast<const float4*>(xr);
    const float4 x1 = *reinterpret_cast<const float4*>(xr + 4);
    acc0.x += fmaxf(a0.x + x0.x, 0.f);
    acc0.y += fmaxf(a0.y + x0.y, 0.f);
    acc0.z += fmaxf(a0.z + x0.z, 0.f);
    acc0.w += fmaxf(a0.w + x0.w, 0.f);
    acc1.x += fmaxf(a1.x + x1.x, 0.f);
    acc1.y += fmaxf(a1.y + x1.y, 0.f);
    acc1.z += fmaxf(a1.z + x1.z, 0.f);
    acc1.w += fmaxf(a1.w + x1.w, 0.f);
  }
#pragma unroll
  for (int m = 8; m <= 32; m <<= 1) {
    acc0.x += __shfl_xor(acc0.x, m);
    acc0.y += __shfl_xor(acc0.y, m);
    acc0.z += __shfl_xor(acc0.z, m);
    acc0.w += __shfl_xor(acc0.w, m);
    acc1.x += __shfl_xor(acc1.x, m);
    acc1.y += __shfl_xor(acc1.y, m);
    acc1.z += __shfl_xor(acc1.z, m);
    acc1.w += __shfl_xor(acc1.w, m);
  }
  if (lane < 8) {
    float* p = agg + (size_t)n * DD + lane * 8;
    *reinterpret_cast<float4*>(p) = acc0;
    *reinterpret_cast<float4*>(p + 4) = acc1;
  }
}

// ---------------- fallback edge pass (atomic) if ws too small -------------
__global__ __launch_bounds__(256) void edge_kernel(
    const float* __restrict__ x, const int* __restrict__ ei,
    const float* __restrict__ ea, float* __restrict__ agg_in,
    float* __restrict__ agg_out) {
  const int tid = blockIdx.x * 256 + threadIdx.x;
  const int e = tid >> 4;
  if (e >= NE) return;
  const int c = (tid & 15) * 4;
  const int s = ei[e];
  const int d = ei[NE + e];
  const float4 a = *reinterpret_cast<const float4*>(ea + (size_t)e * DD + c);
  const float4 xs = *reinterpret_cast<const float4*>(x + (size_t)s * DD + c);
  const float4 xd = *reinterpret_cast<const float4*>(x + (size_t)d * DD + c);
  float* pi = agg_in + (size_t)d * DD + c;
  unsafeAtomicAdd(pi + 0, fmaxf(xs.x + a.x, 0.f));
  unsafeAtomicAdd(pi + 1, fmaxf(xs.y + a.y, 0.f));
  unsafeAtomicAdd(pi + 2, fmaxf(xs.z + a.z, 0.f));
  unsafeAtomicAdd(pi + 3, fmaxf(xs.w + a.w, 0.f));
  float* po = agg_out + (size_t)s * DD + c;
  unsafeAtomicAdd(po + 0, fmaxf(xd.x + a.x, 0.f));
  unsafeAtomicAdd(po + 1, fmaxf(xd.y + a.y, 0.f));
  unsafeAtomicAdd(po + 2, fmaxf(xd.z + a.z, 0.f));
  unsafeAtomicAdd(po + 3, fmaxf(xd.w + a.w, 0.f));
}

// ---------------- MFMA node MLP + final projection ----------------
__device__ __forceinline__ void mm_pass(const float* At, int wv, int lane,
                                        const unsigned short* __restrict__ whi,
                                        const unsigned short* __restrict__ wlo,
                                        int mat, f32x4_t acc[4]) {
  const int row = (wv << 4) + (lane & 15);
  const int kbase = ((lane >> 4) & 3) << 2;
#pragma unroll
  for (int ks = 0; ks < 2; ++ks) {
    const float* ap = At + row * TSTR + ks * 32 + kbase;
    const float4 g0 = *reinterpret_cast<const float4*>(ap);
    const float4 g1 = *reinterpret_cast<const float4*>(ap + 16);
    const float gv[8] = {g0.x, g0.y, g0.z, g0.w, g1.x, g1.y, g1.z, g1.w};
    bf16x8_t ahi, alo;
#pragma unroll
    for (int i = 0; i < 8; ++i) {
      unsigned short h, l;
      split_bf16(gv[i], h, l);
      ahi[i] = (short)h;
      alo[i] = (short)l;
    }
#pragma unroll
    for (int ct = 0; ct < 4; ++ct) {
      const int fb = ((mat * 2 + ks) * 4 + ct) * 512 + lane * 8;
      const bf16x8_t wh = *reinterpret_cast<const bf16x8_t*>(whi + fb);
      const bf16x8_t wl = *reinterpret_cast<const bf16x8_t*>(wlo + fb);
      acc[ct] = __builtin_amdgcn_mfma_f32_16x16x32_bf16(ahi, wh, acc[ct], 0, 0, 0);
      acc[ct] = __builtin_amdgcn_mfma_f32_16x16x32_bf16(alo, wh, acc[ct], 0, 0, 0);
      acc[ct] = __builtin_amdgcn_mfma_f32_16x16x32_bf16(ahi, wl, acc[ct], 0, 0, 0);
    }
  }
}

__global__ __launch_bounds__(256) void node_kernel(
    const float* __restrict__ x, const float* __restrict__ agg_in,
    const float* __restrict__ agg_out, const float* __restrict__ b1,
    const float* __restrict__ bc, const unsigned short* __restrict__ whi,
    const unsigned short* __restrict__ wlo, float* __restrict__ out) {
  __shared__ float TA[64 * TSTR];
  __shared__ float TH[64 * TSTR];
  const int t = threadIdx.x;
  const int lane = t & 63;
  const int wv = t >> 6;
  const int n0 = blockIdx.x * 64;

  f32x4_t ofrag[4];
#pragma unroll
  for (int ct = 0; ct < 4; ++ct) ofrag[ct] = (f32x4_t){0.f, 0.f, 0.f, 0.f};
  float b1v[4], bcv[4];
#pragma unroll
  for (int ct = 0; ct < 4; ++ct) {
    b1v[ct] = b1[ct * 16 + (lane & 15)];
    bcv[ct] = bc[ct * 16 + (lane & 15)];
  }

#define LOAD_TILE_F32(SRC)                                                    \
  {                                                                           \
    const int r = t >> 2;                                                     \
    const int cb = (t & 3) * 16;                                              \
    const int n = n0 + r;                                                     \
    _Pragma("unroll") for (int ii = 0; ii < 4; ++ii) {                        \
      float4 v = make_float4(0.f, 0.f, 0.f, 0.f);                             \
      if (n < NN)                                                             \
        v = *reinterpret_cast<const float4*>((SRC) + (size_t)n * DD + cb +    \
                                             ii * 4);                         \
      *reinterpret_cast<float4*>(&TA[r * TSTR + cb + ii * 4]) = v;            \
    }                                                                         \
  }

#define H_PASS(MATW1)                                                         \
  {                                                                           \
    f32x4_t h[4];                                                             \
    _Pragma("unroll") for (int ct = 0; ct < 4; ++ct) h[ct] =                  \
        (f32x4_t){0.f, 0.f, 0.f, 0.f};                                        \
    mm_pass(TA, wv, lane, whi, wlo, (MATW1), h);                              \
    _Pragma("unroll") for (int ct = 0; ct < 4; ++ct)                          \
        _Pragma("unroll") for (int r = 0; r < 4; ++r) {                       \
      const float hv = fmaxf(h[ct][r] + b1v[ct], 0.f);                        \
      TH[((wv << 4) + ((lane >> 4) << 2) + r) * TSTR + ct * 16 +              \
         (lane & 15)] = hv;                                                   \
    }                                                                         \
  }

  LOAD_TILE_F32(agg_in);
  __syncthreads();
  H_PASS(0);
  __syncthreads();
  mm_pass(TH, wv, lane, whi, wlo, 1, ofrag);
  __syncthreads();
  LOAD_TILE_F32(agg_out);
  __syncthreads();
  H_PASS(0);
  __syncthreads();
  mm_pass(TH, wv, lane, whi, wlo, 2, ofrag);
  __syncthreads();
  LOAD_TILE_F32(x);
  __syncthreads();
  mm_pass(TA, wv, lane, whi, wlo, 3, ofrag);

#pragma unroll
  for (int ct = 0; ct < 4; ++ct)
#pragma unroll
    for (int r = 0; r < 4; ++r) {
      const int n = n0 + (wv << 4) + ((lane >> 4) << 2) + r;
      if (n < NN)
        out[(size_t)n * DD + ct * 16 + (lane & 15)] = ofrag[ct][r] + bcv[ct];
    }
}

extern "C" void kernel_launch(void* const* d_in, const int* in_sizes, int n_in,
                              void* d_out, int out_size, void* d_ws,
                              size_t ws_size, hipStream_t stream) {
  const float* x = (const float*)d_in[0];
  const int* ei = (const int*)d_in[1];
  const float* ea = (const float*)d_in[2];
  const float* W1 = (const float*)d_in[3];
  const float* b1 = (const float*)d_in[4];
  const float* W2 = (const float*)d_in[5];
  const float* b2 = (const float*)d_in[6];
  const float* Wl = (const float*)d_in[7];
  const float* bl = (const float*)d_in[8];
  float* out = (float*)d_out;
  float* ws = (float*)d_ws;

  const size_t REG = (size_t)NCNT2 * SORT_CAP;      // 3,203,072 records
  // layout (16B-aligned segments)
  float* agg_in = ws;                               // NN*DD f32
  float* agg_out = agg_in + (size_t)NN * DD;        // NN*DD f32
  int2* tmp = (int2*)(agg_out + (size_t)NN * DD);   // REG int2 (25.6 MB)
  int2* lst2 = tmp + REG;                           // REG int2 (25.6 MB)
  int* offb_d = (int*)(lst2 + REG);                 // NN+4
  int* offe_d = offb_d + NN + 4;                    // NN+4
  int* offb_s = offe_d + NN + 4;                    // NN+4
  int* offe_s = offb_s + NN + 4;                    // NN+4
  int* bcur2 = offe_s + NN + 4;                     // NCNT2 (+pad)
  float* Wc1 = (float*)(bcur2 + NCNT2 + 10);
  float* Wc2 = Wc1 + 4096;
  float* bc = Wc2 + 4096;
  unsigned short* whi = (unsigned short*)(bc + 64);  // 4*4096 bf16
  unsigned short* wlo = whi + 4 * 4096;              // 4*4096 bf16
  const size_t need = (size_t)((char*)(wlo + 4 * 4096) - (char*)ws);  // ~105 MB

  const bool bkt_ok = ws_size >= need;
  if (!bkt_ok) {
    Wc1 = agg_out + (size_t)NN * DD;
    Wc2 = Wc1 + 4096;
    bc = Wc2 + 4096;
    whi = (unsigned short*)(bc + 64);
    wlo = whi + 4 * 4096;
  }

  precompute_kernel<<<32, 256, 0, stream>>>(W2, b2, Wl, bl, Wc1, Wc2, bc);
  pack_w_kernel<<<64, 256, 0, stream>>>(W1, Wl, Wc1, Wc2, whi, wlo);

  if (bkt_ok) {
    hipMemsetAsync(bcur2, 0, NCNT2 * sizeof(int), stream);
    multisplit_kernel<<<2 * NCHUNK, 256, 0, stream>>>(ei, bcur2, tmp);
    bucket_sort_kernel<<<2 * NBKT, 512, 0, stream>>>(
        tmp, bcur2, offb_d, offe_d, offb_s, offe_s, lst2);
    gather_kernel<<<2 * GNB, 256, 0, stream>>>(x, ea, offb_d, offe_d, offb_s,
                                               offe_s, lst2, agg_in, agg_out);
  } else {
    hipMemsetAsync(agg_in, 0, 2 * (size_t)NN * DD * sizeof(float), stream);
    edge_kernel<<<((size_t)NE * 16 + 255) / 256, 256, 0, stream>>>(
        x, ei, ea, agg_in, agg_out);
  }

  node_kernel<<<(NN + 63) / 64, 256, 0, stream>>>(x, agg_in, agg_out, b1, bc,
                                                  whi, wlo, out);
}